// Round 1
// baseline (1341.869 us; speedup 1.0000x reference)
//
#include <hip/hip_runtime.h>
#include <hip/hip_bf16.h>
#include <cstdint>
#include <cstddef>

#define Bb 16
#define Kk 2048
#define Pp 512
#define Ss 16
#define Cc 256
#define HEADOUT 325

// ---------------- workspace layout (bytes) ----------------
static constexpr size_t OFF_TNORM = 0;                        // 10*512*4 = 20480
static constexpr size_t OFF_SUMS  = 20480;                    // 16384
static constexpr size_t OFF_INDS  = OFF_SUMS + 16384;         // 8192*4
static constexpr size_t OFF_IDXL  = OFF_INDS + 32768;         // 131072*4
static constexpr size_t OFF_GX    = OFF_IDXL + 524288;        // 131072*3*4
static constexpr size_t OFF_F1    = OFF_GX + 1572864;         // 32768*128*4
static constexpr size_t OFF_BIGA  = OFF_F1 + 16777216;        // 131072*128*4
static constexpr size_t OFF_BIGB  = OFF_BIGA + 67108864;      // 131072*128*4
static constexpr size_t OFF_FEAT  = OFF_BIGB + 67108864;      // 8192*128*4
static constexpr size_t OFF_C1    = OFF_FEAT + 4194304;
static constexpr size_t OFF_C2    = OFF_C1 + 4194304;
static constexpr size_t OFF_NET   = OFF_C2 + 4194304;         // 8192*325*4

// sum-slot float offsets inside OFF_SUMS
#define SB0S 0
#define SB0Q 128
#define SB1S 256
#define SB1Q 384
#define SB2S 512
#define SB2Q 640
#define SC1S 768
#define SC1Q 896
#define SC2S 1024
#define SC2Q 1152
#define SH0S 1280
#define SH0Q 1792
#define SH1S 2304
#define SH1Q 2816

// ---------------- text-feature normalization ----------------
__global__ __launch_bounds__(640) void tnorm_k(const float* __restrict__ tf,
                                               float* __restrict__ tn) {
  int w = threadIdx.x >> 6, lane = threadIdx.x & 63;
  const float* r = tf + (size_t)w * 512;
  float v[8];
  float ss = 0.f;
  #pragma unroll
  for (int u = 0; u < 8; u++) { v[u] = r[lane + 64 * u]; ss += v[u] * v[u]; }
  #pragma unroll
  for (int off = 32; off; off >>= 1) ss += __shfl_xor(ss, off, 64);
  float nrm = sqrtf(ss);
  #pragma unroll
  for (int u = 0; u < 8; u++) tn[(size_t)w * 512 + lane + 64 * u] = v[u] / nrm;
}

// ---------------- farthest point sampling ----------------
// exact replica of the reference scan: d computed without FMA contraction,
// argmax = first index of max (packed-key max with ~idx tiebreak).
__global__ __launch_bounds__(256) void fps_kernel(const float* __restrict__ xyz,
                                                  int* __restrict__ inds) {
  int b = blockIdx.x;
  __shared__ float px[Kk], py[Kk], pz[Kk];
  __shared__ unsigned long long redw[4];
  __shared__ int s_last;
  const float* base = xyz + (size_t)b * Kk * 3;
  for (int i = threadIdx.x; i < Kk; i += 256) {
    px[i] = base[3 * i]; py[i] = base[3 * i + 1]; pz[i] = base[3 * i + 2];
  }
  if (threadIdx.x == 0) { inds[b * Pp] = 0; s_last = 0; }
  __syncthreads();
  float dmin[8];
  #pragma unroll
  for (int j = 0; j < 8; j++) dmin[j] = 1e10f;
  const int lane = threadIdx.x & 63, wid = threadIdx.x >> 6;
  for (int it = 1; it < Pp; ++it) {
    int last = s_last;
    float lx = px[last], ly = py[last], lz = pz[last];
    unsigned long long best = 0ull;
    #pragma unroll
    for (int j = 0; j < 8; j++) {
      int k = threadIdx.x + j * 256;
      float dx = px[k] - lx, dy = py[k] - ly, dz = pz[k] - lz;
      float d = __fadd_rn(__fadd_rn(__fmul_rn(dx, dx), __fmul_rn(dy, dy)),
                          __fmul_rn(dz, dz));
      float dm = fminf(dmin[j], d);
      dmin[j] = dm;
      unsigned long long key =
          ((unsigned long long)__float_as_uint(dm) << 32) | (unsigned)(~k);
      best = (key > best) ? key : best;
    }
    #pragma unroll
    for (int off = 32; off; off >>= 1) {
      unsigned long long o = __shfl_xor(best, off, 64);
      best = (o > best) ? o : best;
    }
    if (lane == 0) redw[wid] = best;
    __syncthreads();
    if (threadIdx.x == 0) {
      unsigned long long m0 = redw[0] > redw[1] ? redw[0] : redw[1];
      unsigned long long m1 = redw[2] > redw[3] ? redw[2] : redw[3];
      unsigned long long mm = m0 > m1 ? m0 : m1;
      int nxt = (int)(~(unsigned)mm);
      s_last = nxt;
      inds[b * Pp + it] = nxt;
    }
    __syncthreads();
  }
}

// ---------------- neighbor selection (first S ascending within radius) ------
__global__ __launch_bounds__(256) void neigh_k(const float* __restrict__ xyz,
                                               const int* __restrict__ inds,
                                               int* __restrict__ idxl,
                                               float* __restrict__ gx) {
  int widx = blockIdx.x * 4 + (threadIdx.x >> 6);
  int lane = threadIdx.x & 63;
  int b = widx >> 9;
  int q = inds[widx];
  const float* base = xyz + (size_t)b * Kk * 3;
  float qx = base[3 * q], qy = base[3 * q + 1], qz = base[3 * q + 2];
  int cnt = 0;
  int myk = 0;
  for (int ch = 0; ch < 32 && cnt < Ss; ch++) {
    int k = ch * 64 + lane;
    float dx = base[3 * k] - qx;
    float dy = base[3 * k + 1] - qy;
    float dz = base[3 * k + 2] - qz;
    float d2 = __fadd_rn(__fadd_rn(__fmul_rn(dx, dx), __fmul_rn(dy, dy)),
                         __fmul_rn(dz, dz));
    unsigned long long m = __ballot(d2 < 0.09f);
    while (m && cnt < Ss) {
      int t = __builtin_ctzll(m);
      if (lane == cnt) myk = ch * 64 + t;
      cnt++;
      m &= m - 1;
    }
  }
  int first = __shfl(myk, 0, 64);
  if (lane < Ss) {
    int kk = (lane < cnt) ? myk : first;
    size_t o = (size_t)widx * Ss + lane;
    idxl[o] = kk;
    gx[o * 3 + 0] = (base[3 * kk] - qx) / 0.3f;
    gx[o * 3 + 1] = (base[3 * kk + 1] - qy) / 0.3f;
    gx[o * 3 + 2] = (base[3 * kk + 2] - qz) / 0.3f;
  }
}

// ---------------- generic f32 GEMM: C = act_in(A) @ W (+bias), opt col-sums -
// ASRC 0: A dense row-major (lda). ASRC 1: A = features (B,C,K), row m=(b,k).
// INBN: input transform relu(x*sc+sh) with sc/sh from running sums.
template <int KD, int ASRC, bool INBN, bool HASBIAS, bool OSUM>
__global__ __launch_bounds__(256) void gemm_f32(
    const float* __restrict__ A, int lda, const float* __restrict__ W, int N,
    const float* __restrict__ bias, const float* __restrict__ isum,
    const float* __restrict__ isq, float inv_cnt,
    const float* __restrict__ gamma, const float* __restrict__ beta,
    float* __restrict__ Cout, int ldc, float* __restrict__ osum,
    float* __restrict__ osq) {
  __shared__ float a_t[32][68];
  __shared__ float b_t[32][128];
  __shared__ float sc[INBN ? KD : 1];
  __shared__ float sh[INBN ? KD : 1];
  __shared__ float red_s[128];
  __shared__ float red_q[128];
  const int tid = threadIdx.x;
  const int m0 = blockIdx.x * 64;
  const int n0 = blockIdx.y * 128;
  if (INBN) {
    for (int c = tid; c < KD; c += 256) {
      float mean = isum[c] * inv_cnt;
      float var = isq[c] * inv_cnt - mean * mean;
      float is_ = rsqrtf(var + 1e-5f);
      float scl = gamma[c] * is_;
      sc[c] = scl;
      sh[c] = beta[c] - mean * scl;
    }
  }
  if (OSUM && tid < 128) { red_s[tid] = 0.f; red_q[tid] = 0.f; }
  __syncthreads();

  float acc[4][8];
  #pragma unroll
  for (int i = 0; i < 4; i++)
    #pragma unroll
    for (int j = 0; j < 8; j++) acc[i][j] = 0.f;

  const int ty = tid >> 4, tx = tid & 15;

  for (int c0 = 0; c0 < KD; c0 += 32) {
    if (ASRC == 0) {
      const int lr = tid >> 2, lcs = tid & 3;
      #pragma unroll
      for (int i = 0; i < 8; i++) {
        int c = c0 + lcs + 4 * i;
        float v = A[(size_t)(m0 + lr) * lda + c];
        if (INBN) v = fmaxf(fmaf(v, sc[c], sh[c]), 0.f);
        a_t[lcs + 4 * i][lr] = v;
      }
    } else {
      const int lr = tid & 63, wv = tid >> 6;
      const int b = m0 >> 11, k0 = m0 & 2047;
      const float* fb = A + (size_t)b * (Cc * Kk);
      #pragma unroll
      for (int i = 0; i < 8; i++) {
        int c = c0 + wv + 4 * i;
        a_t[wv + 4 * i][lr] = fb[(size_t)c * Kk + k0 + lr];
      }
    }
    {
      #pragma unroll
      for (int p = 0; p < 4; p++) {
        int cc = p * 8 + (tid >> 5);
        int nl = (tid & 31) * 4;
        #pragma unroll
        for (int u = 0; u < 4; u++) {
          int n = n0 + nl + u;
          b_t[cc][nl + u] = (n < N) ? W[(size_t)(c0 + cc) * N + n] : 0.f;
        }
      }
    }
    __syncthreads();
    #pragma unroll
    for (int kk = 0; kk < 32; kk++) {
      float4 av = *(const float4*)&a_t[kk][ty * 4];
      float4 b0 = *(const float4*)&b_t[kk][tx * 4];
      float4 b1 = *(const float4*)&b_t[kk][tx * 4 + 64];
      float ap[4] = {av.x, av.y, av.z, av.w};
      float bq0[4] = {b0.x, b0.y, b0.z, b0.w};
      float bq1[4] = {b1.x, b1.y, b1.z, b1.w};
      #pragma unroll
      for (int i = 0; i < 4; i++) {
        #pragma unroll
        for (int u = 0; u < 4; u++) {
          acc[i][u] = fmaf(ap[i], bq0[u], acc[i][u]);
          acc[i][4 + u] = fmaf(ap[i], bq1[u], acc[i][4 + u]);
        }
      }
    }
    __syncthreads();
  }

  float ps[8], pq[8];
  #pragma unroll
  for (int j = 0; j < 8; j++) { ps[j] = 0.f; pq[j] = 0.f; }
  const bool full = (n0 + 128 <= N);
  #pragma unroll
  for (int i = 0; i < 4; i++) {
    size_t m = (size_t)(m0 + ty * 4 + i);
    #pragma unroll
    for (int g = 0; g < 2; g++) {
      float tmp[4];
      #pragma unroll
      for (int u = 0; u < 4; u++) {
        int j = g * 4 + u;
        int n = n0 + g * 64 + tx * 4 + u;
        float v = acc[i][j];
        if (HASBIAS && n < N) v += bias[n];
        tmp[u] = v;
        if (OSUM) { ps[j] += v; pq[j] += v * v; }
      }
      if (full) {
        float4 v4 = make_float4(tmp[0], tmp[1], tmp[2], tmp[3]);
        *(float4*)&Cout[m * ldc + n0 + g * 64 + tx * 4] = v4;
      } else {
        #pragma unroll
        for (int u = 0; u < 4; u++) {
          int n = n0 + g * 64 + tx * 4 + u;
          if (n < N) Cout[m * ldc + n] = tmp[u];
        }
      }
    }
  }
  if (OSUM) {
    #pragma unroll
    for (int g = 0; g < 2; g++)
      #pragma unroll
      for (int u = 0; u < 4; u++) {
        atomicAdd(&red_s[g * 64 + tx * 4 + u], ps[g * 4 + u]);
        atomicAdd(&red_q[g * 64 + tx * 4 + u], pq[g * 4 + u]);
      }
    __syncthreads();
    if (tid < 128) {
      atomicAdd(&osum[n0 + tid], red_s[tid]);
      atomicAdd(&osq[n0 + tid], red_q[tid]);
    }
  }
}

// ---------------- gather layer-1: L1 = F1[gather] + gx @ W0_xyz, + bn0 sums -
__global__ __launch_bounds__(256) void gather_l1(
    const float* __restrict__ F1, const int* __restrict__ idxl,
    const float* __restrict__ gx, const float* __restrict__ g_w0,
    float* __restrict__ L1, float* __restrict__ s0, float* __restrict__ q0) {
  int col = threadIdx.x & 127, half = threadIdx.x >> 7;
  int row0 = blockIdx.x * 64 + half * 32;
  float w0 = g_w0[col], w1 = g_w0[128 + col], w2 = g_w0[256 + col];
  __shared__ float rs[128], rq[128];
  if (threadIdx.x < 128) { rs[threadIdx.x] = 0.f; rq[threadIdx.x] = 0.f; }
  __syncthreads();
  float s = 0.f, q = 0.f;
  for (int rr = 0; rr < 32; rr++) {
    int row = row0 + rr;
    int b = row >> 13;  // 8192 rows per batch
    int idx = idxl[row];
    float g0 = gx[(size_t)row * 3], g1 = gx[(size_t)row * 3 + 1],
          g2 = gx[(size_t)row * 3 + 2];
    float v = F1[((size_t)(b * Kk + idx)) * 128 + col] + g0 * w0 + g1 * w1 +
              g2 * w2;
    L1[(size_t)row * 128 + col] = v;
    s += v;
    q += v * v;
  }
  atomicAdd(&rs[col], s);
  atomicAdd(&rq[col], q);
  __syncthreads();
  if (threadIdx.x < 128) {
    atomicAdd(&s0[threadIdx.x], rs[threadIdx.x]);
    atomicAdd(&q0[threadIdx.x], rq[threadIdx.x]);
  }
}

// ---------------- bn + relu + max over S ----------------
__global__ __launch_bounds__(256) void maxpool_bn(
    const float* __restrict__ L3, const float* __restrict__ s2,
    const float* __restrict__ q2, const float* __restrict__ gam,
    const float* __restrict__ bet, float* __restrict__ feat) {
  int col = threadIdx.x & 127, half = threadIdx.x >> 7;
  int bq = blockIdx.x * 2 + half;
  float mean = s2[col] * (1.f / 131072.f);
  float var = q2[col] * (1.f / 131072.f) - mean * mean;
  float is_ = rsqrtf(var + 1e-5f);
  float scl = gam[col] * is_, shf = bet[col] - mean * scl;
  float m = -1e30f;
  #pragma unroll
  for (int s_ = 0; s_ < Ss; s_++) {
    float v = L3[((size_t)bq * Ss + s_) * 128 + col];
    v = fmaxf(fmaf(v, scl, shf), 0.f);
    m = fmaxf(m, v);
  }
  feat[(size_t)bq * 128 + col] = m;
}

// ---------------- final: normalize q, logits, transpose-assemble ------------
__global__ __launch_bounds__(64) void final_k(const float* __restrict__ net,
                                              const float* __restrict__ qbuf,
                                              const float* __restrict__ tn,
                                              float* __restrict__ out) {
  int bp = blockIdx.x;
  int lane = threadIdx.x;
  int b = bp >> 9, p = bp & 511;
  const float* qr = qbuf + (size_t)bp * 512;
  float qv[8];
  float ss = 0.f;
  #pragma unroll
  for (int u = 0; u < 8; u++) { qv[u] = qr[lane + 64 * u]; ss += qv[u] * qv[u]; }
  #pragma unroll
  for (int off = 32; off; off >>= 1) ss += __shfl_xor(ss, off, 64);
  float inv = 1.f / sqrtf(ss);
  float* ob = out + (size_t)b * 79 * 512 + p;
  const float* nr = net + (size_t)bp * 325;
  for (int ch = lane; ch < 69; ch += 64) ob[(size_t)ch * 512] = nr[ch];
  for (int t = 0; t < 10; t++) {
    const float* tr = tn + (size_t)t * 512;
    float s = 0.f;
    #pragma unroll
    for (int u = 0; u < 8; u++) s += qv[u] * tr[lane + 64 * u];
    #pragma unroll
    for (int off = 32; off; off >>= 1) s += __shfl_xor(s, off, 64);
    if (lane == t) ob[(size_t)(69 + t) * 512] = (float)(1.0 / 0.07) * s * inv;
  }
}

extern "C" void kernel_launch(void* const* d_in, const int* in_sizes, int n_in,
                              void* d_out, int out_size, void* d_ws,
                              size_t ws_size, hipStream_t stream) {
  const float* xyz = (const float*)d_in[0];
  const float* features = (const float*)d_in[1];
  const float* text = (const float*)d_in[2];
  const float* g_w0 = (const float*)d_in[3];
  const float* g_w1 = (const float*)d_in[4];
  const float* g_w2 = (const float*)d_in[5];
  const float* g_gam0 = (const float*)d_in[6];
  const float* g_bet0 = (const float*)d_in[7];
  const float* g_gam1 = (const float*)d_in[8];
  const float* g_bet1 = (const float*)d_in[9];
  const float* g_gam2 = (const float*)d_in[10];
  const float* g_bet2 = (const float*)d_in[11];
  const float* conv1_w = (const float*)d_in[12];
  const float* conv1_b = (const float*)d_in[13];
  const float* bn1_g = (const float*)d_in[14];
  const float* bn1_b = (const float*)d_in[15];
  const float* conv2_w = (const float*)d_in[16];
  const float* conv2_b = (const float*)d_in[17];
  const float* bn2_g = (const float*)d_in[18];
  const float* bn2_b = (const float*)d_in[19];
  const float* conv3_w = (const float*)d_in[20];
  const float* conv3_b = (const float*)d_in[21];
  const float* h_w0 = (const float*)d_in[22];
  const float* h_b0 = (const float*)d_in[23];
  const float* h_g0 = (const float*)d_in[24];
  const float* h_be0 = (const float*)d_in[25];
  const float* h_w1 = (const float*)d_in[26];
  const float* h_b1 = (const float*)d_in[27];
  const float* h_g1 = (const float*)d_in[28];
  const float* h_be1 = (const float*)d_in[29];
  const float* h_w2 = (const float*)d_in[30];
  const float* h_b2 = (const float*)d_in[31];
  float* out = (float*)d_out;
  char* ws = (char*)d_ws;

  float* tn = (float*)(ws + OFF_TNORM);
  float* sums = (float*)(ws + OFF_SUMS);
  int* inds = (int*)(ws + OFF_INDS);
  int* idxl = (int*)(ws + OFF_IDXL);
  float* gx = (float*)(ws + OFF_GX);
  float* F1 = (float*)(ws + OFF_F1);
  float* BIGA = (float*)(ws + OFF_BIGA);
  float* BIGB = (float*)(ws + OFF_BIGB);
  float* feat = (float*)(ws + OFF_FEAT);
  float* c1 = (float*)(ws + OFF_C1);
  float* c2 = (float*)(ws + OFF_C2);
  float* net = (float*)(ws + OFF_NET);

  hipMemsetAsync(sums, 0, 16384, stream);
  tnorm_k<<<1, 640, 0, stream>>>(text, tn);
  fps_kernel<<<16, 256, 0, stream>>>(xyz, inds);
  neigh_k<<<2048, 256, 0, stream>>>(xyz, inds, idxl, gx);
  // F1 = feats_kc @ g_w0[3:, :]   (32768 x 256 x 128)
  gemm_f32<256, 1, false, false, false><<<dim3(512, 1), 256, 0, stream>>>(
      features, 0, g_w0 + 3 * 128, 128, nullptr, nullptr, nullptr, 0.f,
      nullptr, nullptr, F1, 128, nullptr, nullptr);
  // L1 = gather(F1) + gx @ g_w0[:3, :]  (+ bn0 sums)
  gather_l1<<<2048, 256, 0, stream>>>(F1, idxl, gx, g_w0, BIGA, sums + SB0S,
                                      sums + SB0Q);
  // L2 = relu(bn0(L1)) @ g_w1  (+ bn1 sums)
  gemm_f32<128, 0, true, false, true><<<dim3(2048, 1), 256, 0, stream>>>(
      BIGA, 128, g_w1, 128, nullptr, sums + SB0S, sums + SB0Q, 1.f / 131072.f,
      g_gam0, g_bet0, BIGB, 128, sums + SB1S, sums + SB1Q);
  // L3 = relu(bn1(L2)) @ g_w2  (+ bn2 sums)
  gemm_f32<128, 0, true, false, true><<<dim3(2048, 1), 256, 0, stream>>>(
      BIGB, 128, g_w2, 128, nullptr, sums + SB1S, sums + SB1Q, 1.f / 131072.f,
      g_gam1, g_bet1, BIGA, 128, sums + SB2S, sums + SB2Q);
  // feat = max_s relu(bn2(L3))
  maxpool_bn<<<4096, 256, 0, stream>>>(BIGA, sums + SB2S, sums + SB2Q, g_gam2,
                                       g_bet2, feat);
  // c1 = feat @ conv1_w + b  (+ sums)
  gemm_f32<128, 0, false, true, true><<<dim3(128, 1), 256, 0, stream>>>(
      feat, 128, conv1_w, 128, conv1_b, nullptr, nullptr, 0.f, nullptr,
      nullptr, c1, 128, sums + SC1S, sums + SC1Q);
  // c2 = relu(bn(c1)) @ conv2_w + b  (+ sums)
  gemm_f32<128, 0, true, true, true><<<dim3(128, 1), 256, 0, stream>>>(
      c1, 128, conv2_w, 128, conv2_b, sums + SC1S, sums + SC1Q, 1.f / 8192.f,
      bn1_g, bn1_b, c2, 128, sums + SC2S, sums + SC2Q);
  // net = relu(bn(c2)) @ conv3_w + b   (N = 325)
  gemm_f32<128, 0, true, true, false><<<dim3(128, 3), 256, 0, stream>>>(
      c2, 128, conv3_w, 325, conv3_b, sums + SC2S, sums + SC2Q, 1.f / 8192.f,
      bn2_g, bn2_b, net, 325, nullptr, nullptr);
  // h0 = clip_in @ h_w0 + b (clip_in = net[:, 69:325])
  gemm_f32<256, 0, false, true, true><<<dim3(128, 4), 256, 0, stream>>>(
      net + 69, 325, h_w0, 512, h_b0, nullptr, nullptr, 0.f, nullptr, nullptr,
      BIGB, 512, sums + SH0S, sums + SH0Q);
  // h1 = relu(bn(h0)) @ h_w1 + b
  gemm_f32<512, 0, true, true, true><<<dim3(128, 4), 256, 0, stream>>>(
      BIGB, 512, h_w1, 512, h_b1, sums + SH0S, sums + SH0Q, 1.f / 8192.f, h_g0,
      h_be0, BIGA, 512, sums + SH1S, sums + SH1Q);
  // q = relu(bn(h1)) @ h_w2 + b
  gemm_f32<512, 0, true, true, false><<<dim3(128, 4), 256, 0, stream>>>(
      BIGA, 512, h_w2, 512, h_b2, sums + SH1S, sums + SH1Q, 1.f / 8192.f, h_g1,
      h_be1, BIGB, 512, nullptr, nullptr);
  final_k<<<8192, 64, 0, stream>>>(net, BIGB, tn, out);
}